// Round 2
// baseline (79.168 us; speedup 1.0000x reference)
//
#include <hip/hip_runtime.h>
#include <hip/hip_bf16.h>
#include <math.h>

#define N_DENSE 13
#define N_SPARSE 26
#define SPARSE_DIM 100
#define N_FIELD 39               // 13 + 26
#define KDIM 16
#define N_FEATURES 2613          // 13 + 26*100
#define ROW_F (N_FIELD * KDIM)   // 624 elements per feature row of v
#define ROW_CH 78                // 16B chunks (8 bf16) per feature row
#define THREADS 256
#define ROWS_PER_BLOCK 8         // 32 lanes per row (bf16 kernel)

// ---------------- pre-pass: fp32 -> packed bf16 ----------------
__global__ __launch_bounds__(256) void cvt_bf16(
    const float* __restrict__ v, unsigned int* __restrict__ o, int npairs)
{
    int stride = gridDim.x * blockDim.x;
    for (int i = blockIdx.x * blockDim.x + threadIdx.x; i < npairs; i += stride) {
        float2 f = reinterpret_cast<const float2*>(v)[i];
        __hip_bfloat16 a = __float2bfloat16(f.x);
        __hip_bfloat16 b = __float2bfloat16(f.y);
        unsigned int lo = *reinterpret_cast<unsigned short*>(&a);
        unsigned int hi = *reinterpret_cast<unsigned short*>(&b);
        o[i] = lo | (hi << 16);
    }
}

// unpack-and-accumulate helpers: uint4 = 8 bf16 (element e in low ushort)
__device__ __forceinline__ void accfma8(float a[8], const uint4 t, float xv) {
    a[0] = fmaf(xv, __uint_as_float(t.x << 16),          a[0]);
    a[1] = fmaf(xv, __uint_as_float(t.x & 0xffff0000u), a[1]);
    a[2] = fmaf(xv, __uint_as_float(t.y << 16),          a[2]);
    a[3] = fmaf(xv, __uint_as_float(t.y & 0xffff0000u), a[3]);
    a[4] = fmaf(xv, __uint_as_float(t.z << 16),          a[4]);
    a[5] = fmaf(xv, __uint_as_float(t.z & 0xffff0000u), a[5]);
    a[6] = fmaf(xv, __uint_as_float(t.w << 16),          a[6]);
    a[7] = fmaf(xv, __uint_as_float(t.w & 0xffff0000u), a[7]);
}
__device__ __forceinline__ void accadd8(float a[8], const uint4 t) {
    a[0] += __uint_as_float(t.x << 16);
    a[1] += __uint_as_float(t.x & 0xffff0000u);
    a[2] += __uint_as_float(t.y << 16);
    a[3] += __uint_as_float(t.y & 0xffff0000u);
    a[4] += __uint_as_float(t.z << 16);
    a[5] += __uint_as_float(t.z & 0xffff0000u);
    a[6] += __uint_as_float(t.w << 16);
    a[7] += __uint_as_float(t.w & 0xffff0000u);
}

// ---------------- main kernel (bf16 table, 32 lanes/row) ----------------
// chunk c (of 78) covers elements 8c..8c+7; field f = c>>1, k-half h = c&1.
// lane l (0..31) owns chunks {l, l+32, l+64(if l<14)} -> all parity l&1.
__global__ __launch_bounds__(THREADS, 4) void ffm_bf16(
    const float* __restrict__ x,     // [B, 39]
    const float* __restrict__ w,     // [2613]
    const float* __restrict__ bias,  // [1]
    const uint4* __restrict__ vb,    // [2613, 78] packed bf16 rows
    float* __restrict__ out,         // [B]
    int B)
{
    __shared__ uint4 ldsDense[N_DENSE * ROW_CH];   // 16224 B
    for (int i = threadIdx.x; i < N_DENSE * ROW_CH; i += THREADS)
        ldsDense[i] = vb[i];
    __syncthreads();

    const int g = threadIdx.x >> 5;
    const int l = threadIdx.x & 31;
    const int row = blockIdx.x * ROWS_PER_BLOCK + g;
    if (row >= B) return;

    const float* xr = x + row * (N_DENSE + N_SPARSE);

    float xd[N_DENSE];
#pragma unroll
    for (int j = 0; j < N_DENSE; ++j) xd[j] = xr[j];

    int nidx[N_SPARSE];
#pragma unroll
    for (int s = 0; s < N_SPARSE; ++s)
        nidx[s] = N_DENSE + s * SPARSE_DIM + (int)xr[N_DENSE + s];

    float a0[8], a1[8], a2[8];
#pragma unroll
    for (int j = 0; j < 8; ++j) { a0[j] = 0.f; a1[j] = 0.f; a2[j] = 0.f; }

    const bool tail = (l < ROW_CH - 64);   // l < 14

    // ---- dense features (LDS broadcast) ----
#pragma unroll
    for (int j = 0; j < N_DENSE; ++j) {
        const uint4* b = ldsDense + j * ROW_CH;
        accfma8(a0, b[l],      xd[j]);
        accfma8(a1, b[l + 32], xd[j]);
        if (tail) accfma8(a2, b[l + 64], xd[j]);
    }

    // ---- sparse features (L2 gather, one-hot weight = 1) ----
#pragma unroll 2
    for (int s = 0; s < N_SPARSE; ++s) {
        const uint4* b = vb + (size_t)nidx[s] * ROW_CH;
        uint4 t0 = b[l];
        uint4 t1 = b[l + 32];
        if (tail) { uint4 t2 = b[l + 64]; accadd8(a2, t2); }
        accadd8(a0, t0);
        accadd8(a1, t1);
    }

    // ---- reductions: per-lane chunks are distinct fields, same k-half ----
    float s8[8], q8[8];
#pragma unroll
    for (int j = 0; j < 8; ++j) {
        s8[j] = a0[j] + a1[j] + a2[j];
        q8[j] = a0[j] * a0[j] + a1[j] * a1[j] + a2[j] * a2[j];
    }
#pragma unroll
    for (int m = 2; m <= 16; m <<= 1) {
#pragma unroll
        for (int j = 0; j < 8; ++j) {
            s8[j] += __shfl_xor(s8[j], m);
            q8[j] += __shfl_xor(q8[j], m);
        }
    }
    float c = 0.f;
#pragma unroll
    for (int j = 0; j < 8; ++j) c += s8[j] * s8[j] - q8[j];
    c += __shfl_xor(c, 1);   // combine the two k-halves

    // ---- linear part ----
    float lin = bias[0];
#pragma unroll
    for (int j = 0; j < N_DENSE; ++j) lin = fmaf(xd[j], w[j], lin);
#pragma unroll
    for (int s = 0; s < N_SPARSE; ++s) lin += w[nidx[s]];

    float logit = lin + 0.5f * c;
    if (l == 0) out[row] = 1.f / (1.f + expf(-logit));
}

// ---------------- fp32 fallback (round-1 kernel, 16 lanes/row) ----------------
#define ROW_Q (ROW_F / 4)
__global__ __launch_bounds__(256) void ffm_fp32(
    const float* __restrict__ x, const float* __restrict__ w,
    const float* __restrict__ bias, const float* __restrict__ v,
    float* __restrict__ out, int B)
{
    __shared__ float ldsDense[N_DENSE * ROW_F];
    const float4* v4 = reinterpret_cast<const float4*>(v);
    float4* lds4 = reinterpret_cast<float4*>(ldsDense);
    for (int i = threadIdx.x; i < N_DENSE * ROW_Q; i += 256) lds4[i] = v4[i];
    __syncthreads();

    const int g = threadIdx.x >> 4, l = threadIdx.x & 15;
    const int row = blockIdx.x * 16 + g;
    if (row >= B) return;
    const float* xr = x + row * (N_DENSE + N_SPARSE);

    float4 acc[10];
#pragma unroll
    for (int i = 0; i < 10; ++i) acc[i] = make_float4(0.f, 0.f, 0.f, 0.f);
#pragma unroll
    for (int j = 0; j < N_DENSE; ++j) {
        float xv = xr[j];
        const float4* b = lds4 + j * ROW_Q;
#pragma unroll
        for (int i = 0; i < 10; ++i)
            if (i < 9 || l < 12) {
                float4 t = b[l + 16 * i];
                acc[i].x += xv * t.x; acc[i].y += xv * t.y;
                acc[i].z += xv * t.z; acc[i].w += xv * t.w;
            }
    }
    int nidx[N_SPARSE];
#pragma unroll
    for (int s = 0; s < N_SPARSE; ++s)
        nidx[s] = N_DENSE + s * SPARSE_DIM + (int)xr[N_DENSE + s];
    for (int s = 0; s < N_SPARSE; ++s) {
        const float4* b = v4 + (size_t)nidx[s] * ROW_Q;
#pragma unroll
        for (int i = 0; i < 10; ++i)
            if (i < 9 || l < 12) {
                float4 t = b[l + 16 * i];
                acc[i].x += t.x; acc[i].y += t.y; acc[i].z += t.z; acc[i].w += t.w;
            }
    }
    float4 s4 = make_float4(0,0,0,0), q4 = make_float4(0,0,0,0);
#pragma unroll
    for (int i = 0; i < 10; ++i) {
        s4.x += acc[i].x; s4.y += acc[i].y; s4.z += acc[i].z; s4.w += acc[i].w;
        q4.x += acc[i].x*acc[i].x; q4.y += acc[i].y*acc[i].y;
        q4.z += acc[i].z*acc[i].z; q4.w += acc[i].w*acc[i].w;
    }
#pragma unroll
    for (int m = 4; m <= 8; m <<= 1) {
        s4.x += __shfl_xor(s4.x,m); s4.y += __shfl_xor(s4.y,m);
        s4.z += __shfl_xor(s4.z,m); s4.w += __shfl_xor(s4.w,m);
        q4.x += __shfl_xor(q4.x,m); q4.y += __shfl_xor(q4.y,m);
        q4.z += __shfl_xor(q4.z,m); q4.w += __shfl_xor(q4.w,m);
    }
    float c = (s4.x*s4.x - q4.x) + (s4.y*s4.y - q4.y) +
              (s4.z*s4.z - q4.z) + (s4.w*s4.w - q4.w);
    c += __shfl_xor(c,1); c += __shfl_xor(c,2);
    float lin = bias[0];
#pragma unroll
    for (int j = 0; j < N_DENSE; ++j) lin += xr[j]*w[j];
#pragma unroll
    for (int s = 0; s < N_SPARSE; ++s) lin += w[nidx[s]];
    float logit = lin + 0.5f*c;
    if (l == 0) out[row] = 1.f/(1.f+expf(-logit));
}

extern "C" void kernel_launch(void* const* d_in, const int* in_sizes, int n_in,
                              void* d_out, int out_size, void* d_ws, size_t ws_size,
                              hipStream_t stream) {
    const float* x    = (const float*)d_in[0];
    const float* w    = (const float*)d_in[1];
    const float* bias = (const float*)d_in[2];
    const float* v    = (const float*)d_in[3];
    float* out = (float*)d_out;

    int B = in_sizes[0] / (N_DENSE + N_SPARSE);
    size_t need = (size_t)N_FEATURES * ROW_CH * sizeof(uint4);  // 3,261,024 B

    if (ws_size >= need) {
        int npairs = N_FEATURES * (ROW_F / 2);                  // 815,256
        cvt_bf16<<<2048, 256, 0, stream>>>(v, (unsigned int*)d_ws, npairs);
        int grid = (B + ROWS_PER_BLOCK - 1) / ROWS_PER_BLOCK;
        ffm_bf16<<<grid, THREADS, 0, stream>>>(x, w, bias, (const uint4*)d_ws, out, B);
    } else {
        int grid = (B + 15) / 16;
        ffm_fp32<<<grid, 256, 0, stream>>>(x, w, bias, v, out, B);
    }
}